// Round 19
// baseline (461.179 us; speedup 1.0000x reference)
//
#include <hip/hip_runtime.h>

// ---------------------------------------------------------------------------
// LRU single step, fused — v20 (v18 + 2-tile grid-stride, exact residency).
//   state = Lambda * x0 + Bn @ u              (complex; stored PLANAR re|im)
//   y     = s_re @ C_re^T - s_im @ C_im^T + u @ D^T
//
// Ladder: v2 192. v7 195. v10/v14 176 (nt-loads). v18 100.5 WIN (-43%):
//  fragment-packed weights -> 1KB coalesced transactions (killed the 16-way
//  gather latency multiplier). v19 135 REGRESS: phase fusion dead twice --
//  compiler pins 64 VGPR; fused phase at 64 regs serializes.
// v20 diagnosis: v18's LDS (50,688B) admits 3 blk/CU -> grid 1024 runs as a
//  768-block round + 256-block STRAGGLER round (1 blk/CU, 2/3 idle), and
//  every block's 1.15MB weight pass is cold. Fix: grid 512 + LDS padded to
//  54,272B (exactly 2 blk/CU) = ONE residency round, no tail; each block
//  grid-strides 2 row-tiles so tile 2's 18 weight phases are L1/L2-WARM.
//  Tile body is byte-identical v18.
// Kept: nt-loads, linear I/O, swapped-operand MFMA, dbuf Sc, packed W1/Wy.
// ---------------------------------------------------------------------------

typedef __attribute__((ext_vector_type(8))) short bf16x8;
typedef __attribute__((ext_vector_type(4))) float f32x4;
typedef unsigned short u16;

#define N_ROWS 32768
#define IN_DIM 256
#define SD 512
#define OUT_DIM 256
#define ROWS 32          // rows (n) per tile
#define NTILES 2         // tiles per block (grid-stride)
#define GRID 512         // one residency round at 2 blk/CU
#define NTHR 512         // 8 waves
#define TP 264           // tile pitch in u16 (256 + 8 pad)
#define YP 260           // y staging pitch in f32
#define SMEM_U16 27136   // 54,272 B -> exactly 2 blocks/CU

#define MFMA16(a, b, c) __builtin_amdgcn_mfma_f32_16x16x32_bf16(a, b, c, 0, 0, 0)

__device__ __align__(16) float g_lam[2 * SD];            // lam_re | lam_im
// fragment-packed: [(phase*8+wv)*2+ht][kk][lane][8]
//   u16 offset = (phase*8+wv)*8192 + ht*4096 + kk*512 + lane*8
__device__ __align__(16) u16   g_W1[1024 * IN_DIM];      // 512 KB
__device__ __align__(16) u16   g_Wy[OUT_DIM * 1280];     // 640 KB (p=0..4)

__device__ __forceinline__ u16 f2b(float f) {
    union { float f; unsigned int u; } v; v.f = f;
    unsigned int r = v.u + 0x7FFFu + ((v.u >> 16) & 1u);   // RNE
    return (u16)(r >> 16);
}
__device__ __forceinline__ ushort4 f2b4(f32x4 v) {
    ushort4 b;
    b.x = f2b(v[0]); b.y = f2b(v[1]); b.z = f2b(v[2]); b.w = f2b(v[3]);
    return b;
}
__device__ __forceinline__ f32x4 b2f4(ushort4 b) {
    union { float f; unsigned int u; } t0, t1, t2, t3;
    t0.u = (unsigned)b.x << 16; t1.u = (unsigned)b.y << 16;
    t2.u = (unsigned)b.z << 16; t3.u = (unsigned)b.w << 16;
    return f32x4{t0.f, t1.f, t2.f, t3.f};
}

// --- combined prep (single launch) -----------------------------------------
__global__ void prep_all(const float* __restrict__ nu_log,
                         const float* __restrict__ theta_log,
                         const float* __restrict__ gamma_log,
                         const float* __restrict__ B_re, const float* __restrict__ B_im,
                         const float* __restrict__ C_re, const float* __restrict__ C_im,
                         const float* __restrict__ D) {
    int b = blockIdx.x, t = threadIdx.x;
    if (b < 1024) {
        // source semantics = chunked-planar; destination fragment-packed.
        int s = b >> 8, q = b & 255;
        int wv = q >> 5, ht = (q >> 4) & 1, l16r = q & 15;
        int kk = t >> 5, quad = (t >> 3) & 3, e = t & 7;
        int j = q & 127;
        int h = s * 128 + j;
        float g = expf(gamma_log[h]);
        const float* src = (q < 128) ? B_re : B_im;
        size_t dst = ((((size_t)(s * 8 + wv) * 2 + ht) * 8 + kk) * 64
                      + quad * 16 + l16r) * 8 + e;
        g_W1[dst] = f2b(src[h * IN_DIM + t] * g);
    } else if (b < 1280) {
        int o = b - 1024;
        int wv2 = o >> 5, ot = (o >> 4) & 1, l16o = o & 15;
        #pragma unroll
        for (int it = 0; it < 5; ++it) {
            int c = it * 256 + t;
            int p = c >> 8, k = c & 255;
            int kk = k >> 5, quad = (k >> 3) & 3, e = k & 7;
            float v;
            if (p < 4) {
                v = (k < 128) ? C_re[o * SD + p * 128 + k]
                              : -C_im[o * SD + p * 128 + (k - 128)];
            } else {
                v = D[o * IN_DIM + k];
            }
            size_t dst = ((((size_t)(p * 8 + wv2) * 2 + ot) * 8 + kk) * 64
                          + quad * 16 + l16o) * 8 + e;
            g_Wy[dst] = f2b(v);
        }
    } else {
        int h = (b - 1280) * 256 + t;          // [0,512)
        float mod = expf(-expf(nu_log[h]));
        float th  = expf(theta_log[h]);
        g_lam[h]      = mod * cosf(th);
        g_lam[SD + h] = mod * sinf(th);
    }
}

// --- main fused kernel ------------------------------------------------------
__global__ __launch_bounds__(NTHR, 4) void lru_main(
    const float* __restrict__ u, const float* __restrict__ x0_re,
    const float* __restrict__ x0_im,
    float* __restrict__ y_out, float* __restrict__ st_out,
    long long st_limit)     // floats available in the state region of d_out
{
    __shared__ __align__(16) u16 SMEM[SMEM_U16];   // 54,272 B -> 2 blk/CU

    u16* Xu  = SMEM;                  // u tile bf16 [32][TP]
    u16* Sc0 = SMEM + ROWS * TP;      // state chunk bf16, ping
    u16* Sc1 = SMEM + 2 * ROWS * TP;  // state chunk bf16, pong

    const int tid  = threadIdx.x;
    const int wv   = tid >> 6;          // [0,8)
    const int lane = tid & 63;
    const int quad = lane >> 4;
    const int l16  = lane & 15;
    const int kq   = quad * 8;

    const int Mb = wv * 32;             // wave's M base within a 256-col chunk

    // linear epilogue / prefetch mapping: 1024 slots (32 rows x 32 j4)
    int en[2], ej[2];
    #pragma unroll
    for (int it = 0; it < 2; ++it) {
        int flat = it * NTHR + tid;
        en[it] = flat >> 5; ej[it] = flat & 31;
    }

    for (int tile = 0; tile < NTILES; ++tile) {
        const size_t n0 = ((size_t)blockIdx.x + (size_t)tile * GRID) * ROWS;

        // prefetch x0 chunk 0 (nt: evict-first, don't thrash weight lines)
        f32x4 xr[2], xi[2];
        #pragma unroll
        for (int it = 0; it < 2; ++it) {
            size_t roff = (n0 + en[it]) * SD + ej[it] * 4;
            xr[it] = __builtin_nontemporal_load((const f32x4*)(x0_re + roff));
            xi[it] = __builtin_nontemporal_load((const f32x4*)(x0_im + roff));
        }

        // stage u tile -> bf16 LDS (32x256, linear nt f32x4 loads)
        #pragma unroll
        for (int i = 0; i < 4; ++i) {
            int it = tid + i * NTHR;              // 2048 items
            int r = it >> 6, c4 = it & 63;
            f32x4 v = __builtin_nontemporal_load(
                (const f32x4*)(u + (n0 + r) * IN_DIM) + c4);
            *(ushort4*)(&Xu[r * TP + c4 * 4]) = f2b4(v);
        }
        __syncthreads();

        f32x4 accy[2][2];
        #pragma unroll
        for (int ot = 0; ot < 2; ++ot)
            #pragma unroll
            for (int nt = 0; nt < 2; ++nt)
                accy[ot][nt] = f32x4{0.f, 0.f, 0.f, 0.f};

        for (int s = 0; s < 4; ++s) {
            u16* Sc = (s & 1) ? Sc1 : Sc0;        // double buffer

            // ---- GEMM-A (swapped): Bu = W1_chunk @ Xu^T (packed 1KB loads)
            f32x4 acc[2][2];
            #pragma unroll
            for (int ht = 0; ht < 2; ++ht)
                #pragma unroll
                for (int nt = 0; nt < 2; ++nt)
                    acc[ht][nt] = f32x4{0.f, 0.f, 0.f, 0.f};
            const u16* w1b = g_W1 + (size_t)(s * 8 + wv) * 8192 + lane * 8;
            #pragma unroll
            for (int kk = 0; kk < 8; ++kk) {
                bf16x8 a[2], b[2];
                #pragma unroll
                for (int ht = 0; ht < 2; ++ht)
                    a[ht] = *(const bf16x8*)(w1b + ht * 4096 + kk * 512);
                #pragma unroll
                for (int nt = 0; nt < 2; ++nt)
                    b[nt] = *(const bf16x8*)(&Xu[(nt * 16 + l16) * TP + kk * 32 + kq]);
                #pragma unroll
                for (int ht = 0; ht < 2; ++ht)
                    #pragma unroll
                    for (int nt = 0; nt < 2; ++nt)
                        acc[ht][nt] = MFMA16(a[ht], b[nt], acc[ht][nt]);
            }
            // fragments -> Sc as bf16 (contiguous ushort4: 4 consec h/lane)
            #pragma unroll
            for (int ht = 0; ht < 2; ++ht)
                #pragma unroll
                for (int nt = 0; nt < 2; ++nt) {
                    const int n  = nt * 16 + l16;
                    const int hM = Mb + ht * 16 + quad * 4;
                    *(ushort4*)(&Sc[n * TP + hM]) = f2b4(acc[ht][nt]);
                }
            __syncthreads();            // barrier A: Sc (Bu bf16) complete

            // ---- linear epilogue: in-place Sc update + contiguous stores
            #pragma unroll
            for (int it = 0; it < 2; ++it) {
                const int n = en[it], j = ej[it];
                f32x4 br  = b2f4(*(const ushort4*)(&Sc[n * TP + j * 4]));
                f32x4 bi  = b2f4(*(const ushort4*)(&Sc[n * TP + 128 + j * 4]));
                f32x4 lre = *(const f32x4*)(g_lam + s * 128 + j * 4);
                f32x4 lim = *(const f32x4*)(g_lam + SD + s * 128 + j * 4);
                f32x4 sr = lre * xr[it] - lim * xi[it] + br;
                f32x4 si = lre * xi[it] + lim * xr[it] + bi;
                const long long ir = (long long)((n0 + n) * SD + s * 128 + j * 4);
                const long long ii = (long long)N_ROWS * SD + ir;
                if (ir + 3 < st_limit) {
                    *(f32x4*)(st_out + ir) = sr;   // cacheable: L3 absorbs
                } else {
                    #pragma unroll
                    for (int k = 0; k < 4; ++k)
                        if (ir + k < st_limit) st_out[ir + k] = sr[k];
                }
                if (ii + 3 < st_limit) {
                    *(f32x4*)(st_out + ii) = si;
                } else {
                    #pragma unroll
                    for (int k = 0; k < 4; ++k)
                        if (ii + k < st_limit) st_out[ii + k] = si[k];
                }
                *(ushort4*)(&Sc[n * TP + j * 4])       = f2b4(sr);
                *(ushort4*)(&Sc[n * TP + 128 + j * 4]) = f2b4(si);
            }

            // prefetch x0 for next chunk BEFORE barrier B (nt)
            if (s < 3) {
                #pragma unroll
                for (int it = 0; it < 2; ++it) {
                    size_t roff = (n0 + en[it]) * SD + (s + 1) * 128 + ej[it] * 4;
                    xr[it] = __builtin_nontemporal_load((const f32x4*)(x0_re + roff));
                    xi[it] = __builtin_nontemporal_load((const f32x4*)(x0_im + roff));
                }
            }
            __syncthreads();            // barrier B: Sc now bf16 state chunk

            // ---- partial y-GEMM (swapped): accy += Wy_chunk @ Sc^T
            const u16* wyb = g_Wy + (size_t)(s * 8 + wv) * 8192 + lane * 8;
            #pragma unroll
            for (int kk = 0; kk < 8; ++kk) {
                bf16x8 a[2], b[2];
                #pragma unroll
                for (int ot = 0; ot < 2; ++ot)
                    a[ot] = *(const bf16x8*)(wyb + ot * 4096 + kk * 512);
                #pragma unroll
                for (int nt = 0; nt < 2; ++nt)
                    b[nt] = *(const bf16x8*)(&Sc[(nt * 16 + l16) * TP + kk * 32 + kq]);
                #pragma unroll
                for (int ot = 0; ot < 2; ++ot)
                    #pragma unroll
                    for (int nt = 0; nt < 2; ++nt)
                        accy[ot][nt] = MFMA16(a[ot], b[nt], accy[ot][nt]);
            }
            // no barrier: next chunk writes the OTHER Sc buffer
        }

        // ---- y u-part: accy += D @ Xu^T  (packed phase p = 4)
        {
            const u16* wdb = g_Wy + (size_t)(4 * 8 + wv) * 8192 + lane * 8;
            #pragma unroll
            for (int kk = 0; kk < 8; ++kk) {
                bf16x8 a[2], b[2];
                #pragma unroll
                for (int ot = 0; ot < 2; ++ot)
                    a[ot] = *(const bf16x8*)(wdb + ot * 4096 + kk * 512);
                #pragma unroll
                for (int nt = 0; nt < 2; ++nt)
                    b[nt] = *(const bf16x8*)(&Xu[(nt * 16 + l16) * TP + kk * 32 + kq]);
                #pragma unroll
                for (int ot = 0; ot < 2; ++ot)
                    #pragma unroll
                    for (int nt = 0; nt < 2; ++nt)
                        accy[ot][nt] = MFMA16(a[ot], b[nt], accy[ot][nt]);
            }
        }

        // ---- y: fragments -> f32 LDS (tiles dead) -> linear store
        __syncthreads();                // everyone done reading Xu/Sc0/Sc1
        float* Yf = (float*)SMEM;       // [32][YP]  (33,280 <= 54,272)
        #pragma unroll
        for (int ot = 0; ot < 2; ++ot)
            #pragma unroll
            for (int nt = 0; nt < 2; ++nt) {
                const int n   = nt * 16 + l16;
                const int col = Mb + ot * 16 + quad * 4;
                *(f32x4*)(&Yf[n * YP + col]) = accy[ot][nt];
            }
        __syncthreads();
        #pragma unroll
        for (int i = 0; i < 4; ++i) {
            int it = tid + i * NTHR;                  // 2048 items
            int r = it >> 6, c4 = it & 63;
            f32x4 v = *(const f32x4*)(&Yf[r * YP + c4 * 4]);
            *(f32x4*)(y_out + (n0 + r) * OUT_DIM + c4 * 4) = v;
        }
        if (tile + 1 < NTILES)
            __syncthreads();            // Yf readers done before restaging Xu
    }
}

extern "C" void kernel_launch(void* const* d_in, const int* in_sizes, int n_in,
                              void* d_out, int out_size, void* d_ws, size_t ws_size,
                              hipStream_t stream) {
    const float* u         = (const float*)d_in[0];
    const float* x0_re     = (const float*)d_in[1];
    const float* x0_im     = (const float*)d_in[2];
    const float* nu_log    = (const float*)d_in[3];
    const float* theta_log = (const float*)d_in[4];
    const float* gamma_log = (const float*)d_in[5];
    const float* B_re      = (const float*)d_in[6];
    const float* B_im      = (const float*)d_in[7];
    const float* C_re      = (const float*)d_in[8];
    const float* C_im      = (const float*)d_in[9];
    const float* D         = (const float*)d_in[10];

    float* y_out  = (float*)d_out;
    float* st_out = y_out + (size_t)N_ROWS * OUT_DIM;
    long long st_limit = (long long)out_size - (long long)N_ROWS * OUT_DIM;

    prep_all<<<1282, 256, 0, stream>>>(nu_log, theta_log, gamma_log,
                                       B_re, B_im, C_re, C_im, D);
    lru_main<<<GRID, NTHR, 0, stream>>>(u, x0_re, x0_im,
                                        y_out, st_out, st_limit);
}

// Round 20
// 278.569 us; speedup vs baseline: 1.6555x; 1.6555x over previous
//
#include <hip/hip_runtime.h>

// ---------------------------------------------------------------------------
// LRU single step, fused — v21 (v18 + LDS pad -> exactly 2 blk/CU).
//   state = Lambda * x0 + Bn @ u              (complex; stored PLANAR re|im)
//   y     = s_re @ C_re^T - s_im @ C_im^T + u @ D^T
//
// Ladder: v2 192. v7 195. v10/v14 176 (nt-loads). v18 100.5 WIN (-43%):
//  fragment-packed weights = 1KB coalesced transactions (killed the 16-way
//  gather latency multiplier). v19 135 REGRESS (fusion dead: VGPR pinned 64).
//  v20 298 REGRESS (grid-stride blurred the row window > L3: 690MB traffic
//  -- third confirmation the concurrent-window-vs-L3 constraint governs).
// v21: single change from v18 -- pad LDS 50,688 -> 54,272 B. v18's 3 blk/CU
//  made grid 1024 run as ~1.33 residency generations with a ragged ~75us
//  tail; 2 blk/CU = exactly 2 clean generations (~50us blocks, short tail)
//  and shrinks the concurrent window 246 -> 160 MB (L3 headroom for
//  weights). v10-vs-v14 showed 2<->3 blk/CU is otherwise neutral.
// Kept: nt-loads, linear I/O, swapped-operand MFMA, dbuf Sc, packed W1/Wy.
// ---------------------------------------------------------------------------

typedef __attribute__((ext_vector_type(8))) short bf16x8;
typedef __attribute__((ext_vector_type(4))) float f32x4;
typedef unsigned short u16;

#define N_ROWS 32768
#define IN_DIM 256
#define SD 512
#define OUT_DIM 256
#define ROWS 32          // rows (n) per block
#define NTHR 512         // 8 waves
#define TP 264           // tile pitch in u16 (256 + 8 pad)
#define YP 260           // y staging pitch in f32
#define SMEM_U16 27136   // 54,272 B -> exactly 2 blocks/CU

#define MFMA16(a, b, c) __builtin_amdgcn_mfma_f32_16x16x32_bf16(a, b, c, 0, 0, 0)

__device__ __align__(16) float g_lam[2 * SD];            // lam_re | lam_im
// fragment-packed: [(phase*8+wv)*2+ht][kk][lane][8]
//   u16 offset = (phase*8+wv)*8192 + ht*4096 + kk*512 + lane*8
__device__ __align__(16) u16   g_W1[1024 * IN_DIM];      // 512 KB
__device__ __align__(16) u16   g_Wy[OUT_DIM * 1280];     // 640 KB (p=0..4)

__device__ __forceinline__ u16 f2b(float f) {
    union { float f; unsigned int u; } v; v.f = f;
    unsigned int r = v.u + 0x7FFFu + ((v.u >> 16) & 1u);   // RNE
    return (u16)(r >> 16);
}
__device__ __forceinline__ ushort4 f2b4(f32x4 v) {
    ushort4 b;
    b.x = f2b(v[0]); b.y = f2b(v[1]); b.z = f2b(v[2]); b.w = f2b(v[3]);
    return b;
}
__device__ __forceinline__ f32x4 b2f4(ushort4 b) {
    union { float f; unsigned int u; } t0, t1, t2, t3;
    t0.u = (unsigned)b.x << 16; t1.u = (unsigned)b.y << 16;
    t2.u = (unsigned)b.z << 16; t3.u = (unsigned)b.w << 16;
    return f32x4{t0.f, t1.f, t2.f, t3.f};
}

// --- combined prep (single launch) -----------------------------------------
__global__ void prep_all(const float* __restrict__ nu_log,
                         const float* __restrict__ theta_log,
                         const float* __restrict__ gamma_log,
                         const float* __restrict__ B_re, const float* __restrict__ B_im,
                         const float* __restrict__ C_re, const float* __restrict__ C_im,
                         const float* __restrict__ D) {
    int b = blockIdx.x, t = threadIdx.x;
    if (b < 1024) {
        // source semantics = chunked-planar; destination fragment-packed.
        int s = b >> 8, q = b & 255;
        int wv = q >> 5, ht = (q >> 4) & 1, l16r = q & 15;
        int kk = t >> 5, quad = (t >> 3) & 3, e = t & 7;
        int j = q & 127;
        int h = s * 128 + j;
        float g = expf(gamma_log[h]);
        const float* src = (q < 128) ? B_re : B_im;
        size_t dst = ((((size_t)(s * 8 + wv) * 2 + ht) * 8 + kk) * 64
                      + quad * 16 + l16r) * 8 + e;
        g_W1[dst] = f2b(src[h * IN_DIM + t] * g);
    } else if (b < 1280) {
        int o = b - 1024;
        int wv2 = o >> 5, ot = (o >> 4) & 1, l16o = o & 15;
        #pragma unroll
        for (int it = 0; it < 5; ++it) {
            int c = it * 256 + t;
            int p = c >> 8, k = c & 255;
            int kk = k >> 5, quad = (k >> 3) & 3, e = k & 7;
            float v;
            if (p < 4) {
                v = (k < 128) ? C_re[o * SD + p * 128 + k]
                              : -C_im[o * SD + p * 128 + (k - 128)];
            } else {
                v = D[o * IN_DIM + k];
            }
            size_t dst = ((((size_t)(p * 8 + wv2) * 2 + ot) * 8 + kk) * 64
                          + quad * 16 + l16o) * 8 + e;
            g_Wy[dst] = f2b(v);
        }
    } else {
        int h = (b - 1280) * 256 + t;          // [0,512)
        float mod = expf(-expf(nu_log[h]));
        float th  = expf(theta_log[h]);
        g_lam[h]      = mod * cosf(th);
        g_lam[SD + h] = mod * sinf(th);
    }
}

// --- main fused kernel ------------------------------------------------------
__global__ __launch_bounds__(NTHR, 4) void lru_main(
    const float* __restrict__ u, const float* __restrict__ x0_re,
    const float* __restrict__ x0_im,
    float* __restrict__ y_out, float* __restrict__ st_out,
    long long st_limit)     // floats available in the state region of d_out
{
    __shared__ __align__(16) u16 SMEM[SMEM_U16];   // 54,272 B -> 2 blk/CU

    u16* Xu  = SMEM;                  // u tile bf16 [32][TP]
    u16* Sc0 = SMEM + ROWS * TP;      // state chunk bf16, ping
    u16* Sc1 = SMEM + 2 * ROWS * TP;  // state chunk bf16, pong

    const int tid  = threadIdx.x;
    const int wv   = tid >> 6;          // [0,8)
    const int lane = tid & 63;
    const int quad = lane >> 4;
    const int l16  = lane & 15;
    const int kq   = quad * 8;
    const size_t n0 = (size_t)blockIdx.x * ROWS;

    const int Mb = wv * 32;             // wave's M base within a 256-col chunk

    // linear epilogue / prefetch mapping: 1024 slots (32 rows x 32 j4)
    int en[2], ej[2];
    #pragma unroll
    for (int it = 0; it < 2; ++it) {
        int flat = it * NTHR + tid;
        en[it] = flat >> 5; ej[it] = flat & 31;
    }

    // prefetch x0 chunk 0 (nt: evict-first, don't thrash weight lines)
    f32x4 xr[2], xi[2];
    #pragma unroll
    for (int it = 0; it < 2; ++it) {
        size_t roff = (n0 + en[it]) * SD + ej[it] * 4;
        xr[it] = __builtin_nontemporal_load((const f32x4*)(x0_re + roff));
        xi[it] = __builtin_nontemporal_load((const f32x4*)(x0_im + roff));
    }

    // stage u tile -> bf16 LDS (32x256, linear nt f32x4 loads)
    #pragma unroll
    for (int i = 0; i < 4; ++i) {
        int it = tid + i * NTHR;              // 2048 items
        int r = it >> 6, c4 = it & 63;
        f32x4 v = __builtin_nontemporal_load(
            (const f32x4*)(u + (n0 + r) * IN_DIM) + c4);
        *(ushort4*)(&Xu[r * TP + c4 * 4]) = f2b4(v);
    }
    __syncthreads();

    f32x4 accy[2][2];
    #pragma unroll
    for (int ot = 0; ot < 2; ++ot)
        #pragma unroll
        for (int nt = 0; nt < 2; ++nt)
            accy[ot][nt] = f32x4{0.f, 0.f, 0.f, 0.f};

    for (int s = 0; s < 4; ++s) {
        u16* Sc = (s & 1) ? Sc1 : Sc0;        // double buffer

        // ---- GEMM-A (swapped): Bu = W1_chunk @ Xu^T (packed 1KB loads)
        f32x4 acc[2][2];
        #pragma unroll
        for (int ht = 0; ht < 2; ++ht)
            #pragma unroll
            for (int nt = 0; nt < 2; ++nt)
                acc[ht][nt] = f32x4{0.f, 0.f, 0.f, 0.f};
        const u16* w1b = g_W1 + (size_t)(s * 8 + wv) * 8192 + lane * 8;
        #pragma unroll
        for (int kk = 0; kk < 8; ++kk) {
            bf16x8 a[2], b[2];
            #pragma unroll
            for (int ht = 0; ht < 2; ++ht)
                a[ht] = *(const bf16x8*)(w1b + ht * 4096 + kk * 512);
            #pragma unroll
            for (int nt = 0; nt < 2; ++nt)
                b[nt] = *(const bf16x8*)(&Xu[(nt * 16 + l16) * TP + kk * 32 + kq]);
            #pragma unroll
            for (int ht = 0; ht < 2; ++ht)
                #pragma unroll
                for (int nt = 0; nt < 2; ++nt)
                    acc[ht][nt] = MFMA16(a[ht], b[nt], acc[ht][nt]);
        }
        // fragments -> Sc as bf16 (contiguous ushort4: lane owns 4 consec h)
        #pragma unroll
        for (int ht = 0; ht < 2; ++ht)
            #pragma unroll
            for (int nt = 0; nt < 2; ++nt) {
                const int n  = nt * 16 + l16;
                const int hM = Mb + ht * 16 + quad * 4;
                *(ushort4*)(&Sc[n * TP + hM]) = f2b4(acc[ht][nt]);
            }
        __syncthreads();            // barrier A: Sc (Bu bf16) complete

        // ---- linear epilogue: in-place Sc update + contiguous f32 stores
        #pragma unroll
        for (int it = 0; it < 2; ++it) {
            const int n = en[it], j = ej[it];
            f32x4 br  = b2f4(*(const ushort4*)(&Sc[n * TP + j * 4]));
            f32x4 bi  = b2f4(*(const ushort4*)(&Sc[n * TP + 128 + j * 4]));
            f32x4 lre = *(const f32x4*)(g_lam + s * 128 + j * 4);
            f32x4 lim = *(const f32x4*)(g_lam + SD + s * 128 + j * 4);
            f32x4 sr = lre * xr[it] - lim * xi[it] + br;
            f32x4 si = lre * xi[it] + lim * xr[it] + bi;
            const long long ir = (long long)((n0 + n) * SD + s * 128 + j * 4);
            const long long ii = (long long)N_ROWS * SD + ir;
            if (ir + 3 < st_limit) {
                *(f32x4*)(st_out + ir) = sr;       // cacheable: L3 absorbs
            } else {
                #pragma unroll
                for (int k = 0; k < 4; ++k)
                    if (ir + k < st_limit) st_out[ir + k] = sr[k];
            }
            if (ii + 3 < st_limit) {
                *(f32x4*)(st_out + ii) = si;
            } else {
                #pragma unroll
                for (int k = 0; k < 4; ++k)
                    if (ii + k < st_limit) st_out[ii + k] = si[k];
            }
            *(ushort4*)(&Sc[n * TP + j * 4])       = f2b4(sr);
            *(ushort4*)(&Sc[n * TP + 128 + j * 4]) = f2b4(si);
        }

        // prefetch x0 for next chunk BEFORE barrier B (nt)
        if (s < 3) {
            #pragma unroll
            for (int it = 0; it < 2; ++it) {
                size_t roff = (n0 + en[it]) * SD + (s + 1) * 128 + ej[it] * 4;
                xr[it] = __builtin_nontemporal_load((const f32x4*)(x0_re + roff));
                xi[it] = __builtin_nontemporal_load((const f32x4*)(x0_im + roff));
            }
        }
        __syncthreads();            // barrier B: Sc now bf16 state chunk

        // ---- partial y-GEMM (swapped): accy += Wy_chunk @ Sc^T
        const u16* wyb = g_Wy + (size_t)(s * 8 + wv) * 8192 + lane * 8;
        #pragma unroll
        for (int kk = 0; kk < 8; ++kk) {
            bf16x8 a[2], b[2];
            #pragma unroll
            for (int ot = 0; ot < 2; ++ot)
                a[ot] = *(const bf16x8*)(wyb + ot * 4096 + kk * 512);
            #pragma unroll
            for (int nt = 0; nt < 2; ++nt)
                b[nt] = *(const bf16x8*)(&Sc[(nt * 16 + l16) * TP + kk * 32 + kq]);
            #pragma unroll
            for (int ot = 0; ot < 2; ++ot)
                #pragma unroll
                for (int nt = 0; nt < 2; ++nt)
                    accy[ot][nt] = MFMA16(a[ot], b[nt], accy[ot][nt]);
        }
        // no barrier: next chunk writes the OTHER Sc buffer
    }

    // ---- y u-part: accy += D @ Xu^T  (packed phase p = 4)
    {
        const u16* wdb = g_Wy + (size_t)(4 * 8 + wv) * 8192 + lane * 8;
        #pragma unroll
        for (int kk = 0; kk < 8; ++kk) {
            bf16x8 a[2], b[2];
            #pragma unroll
            for (int ot = 0; ot < 2; ++ot)
                a[ot] = *(const bf16x8*)(wdb + ot * 4096 + kk * 512);
            #pragma unroll
            for (int nt = 0; nt < 2; ++nt)
                b[nt] = *(const bf16x8*)(&Xu[(nt * 16 + l16) * TP + kk * 32 + kq]);
            #pragma unroll
            for (int ot = 0; ot < 2; ++ot)
                #pragma unroll
                for (int nt = 0; nt < 2; ++nt)
                    accy[ot][nt] = MFMA16(a[ot], b[nt], accy[ot][nt]);
        }
    }

    // ---- y: fragments -> f32 LDS (all tiles dead) -> linear store
    __syncthreads();                // everyone done reading Xu/Sc0/Sc1
    float* Yf = (float*)SMEM;       // [32][YP]  (33,280 <= 54,272)
    #pragma unroll
    for (int ot = 0; ot < 2; ++ot)
        #pragma unroll
        for (int nt = 0; nt < 2; ++nt) {
            const int n   = nt * 16 + l16;
            const int col = Mb + ot * 16 + quad * 4;
            *(f32x4*)(&Yf[n * YP + col]) = accy[ot][nt];
        }
    __syncthreads();
    #pragma unroll
    for (int i = 0; i < 4; ++i) {
        int it = tid + i * NTHR;                  // 2048 items
        int r = it >> 6, c4 = it & 63;
        f32x4 v = *(const f32x4*)(&Yf[r * YP + c4 * 4]);
        *(f32x4*)(y_out + (n0 + r) * OUT_DIM + c4 * 4) = v;
    }
}

extern "C" void kernel_launch(void* const* d_in, const int* in_sizes, int n_in,
                              void* d_out, int out_size, void* d_ws, size_t ws_size,
                              hipStream_t stream) {
    const float* u         = (const float*)d_in[0];
    const float* x0_re     = (const float*)d_in[1];
    const float* x0_im     = (const float*)d_in[2];
    const float* nu_log    = (const float*)d_in[3];
    const float* theta_log = (const float*)d_in[4];
    const float* gamma_log = (const float*)d_in[5];
    const float* B_re      = (const float*)d_in[6];
    const float* B_im      = (const float*)d_in[7];
    const float* C_re      = (const float*)d_in[8];
    const float* C_im      = (const float*)d_in[9];
    const float* D         = (const float*)d_in[10];

    float* y_out  = (float*)d_out;
    float* st_out = y_out + (size_t)N_ROWS * OUT_DIM;
    long long st_limit = (long long)out_size - (long long)N_ROWS * OUT_DIM;

    prep_all<<<1282, 256, 0, stream>>>(nu_log, theta_log, gamma_log,
                                       B_re, B_im, C_re, C_im, D);
    lru_main<<<N_ROWS / ROWS, NTHR, 0, stream>>>(u, x0_re, x0_im,
                                                 y_out, st_out, st_limit);
}